// Round 1
// baseline (1233.377 us; speedup 1.0000x reference)
//
#include <hip/hip_runtime.h>
#include <cstddef>

#define S_LEN 2048
#define NHEAD 16
#define HDIM  64
#define EMB   1024
#define MROWS 4096   // B * S_LEN

__device__ __forceinline__ void fma4x4(float (&acc)[4][4], float4 a, float4 b) {
  acc[0][0] = fmaf(a.x, b.x, acc[0][0]);
  acc[0][1] = fmaf(a.x, b.y, acc[0][1]);
  acc[0][2] = fmaf(a.x, b.z, acc[0][2]);
  acc[0][3] = fmaf(a.x, b.w, acc[0][3]);
  acc[1][0] = fmaf(a.y, b.x, acc[1][0]);
  acc[1][1] = fmaf(a.y, b.y, acc[1][1]);
  acc[1][2] = fmaf(a.y, b.z, acc[1][2]);
  acc[1][3] = fmaf(a.y, b.w, acc[1][3]);
  acc[2][0] = fmaf(a.z, b.x, acc[2][0]);
  acc[2][1] = fmaf(a.z, b.y, acc[2][1]);
  acc[2][2] = fmaf(a.z, b.z, acc[2][2]);
  acc[2][3] = fmaf(a.z, b.w, acc[2][3]);
  acc[3][0] = fmaf(a.w, b.x, acc[3][0]);
  acc[3][1] = fmaf(a.w, b.y, acc[3][1]);
  acc[3][2] = fmaf(a.w, b.z, acc[3][2]);
  acc[3][3] = fmaf(a.w, b.w, acc[3][3]);
}

// Y = X @ W^T + bias.  X:[M,K] rm, W:[N,K] rm (so W^T columns are W rows = contiguous).
// headmajor=1: write Y[m,n] to HM[((b*NHEAD+h)*S_LEN+s)*HDIM+d], m=b*S_LEN+s, n=h*64+d.
// headmajor=0: write Y[m*N+n].
__global__ __launch_bounds__(256) void gemm_bt_f32(
    const float* __restrict__ X, const float* __restrict__ W,
    const float* __restrict__ bias, float* __restrict__ Y,
    int M, int N, int K, int headmajor)
{
  __shared__ __align__(16) float Xs[16][68];  // [k][m], pad 68 keeps float4 alignment
  __shared__ __align__(16) float Ws[16][68];  // [k][n]
  const int tx = threadIdx.x & 15;
  const int ty = threadIdx.x >> 4;
  const int m0 = blockIdx.y * 64;
  const int n0 = blockIdx.x * 64;
  const int lr = threadIdx.x >> 2;        // 0..63: row within tile
  const int lk = (threadIdx.x & 3) * 4;   // 0,4,8,12: k offset
  float acc[4][4] = {};

  for (int k0 = 0; k0 < K; k0 += 16) {
    __syncthreads();
    float4 xv = *(const float4*)&X[(size_t)(m0 + lr) * K + k0 + lk];
    float4 wv = *(const float4*)&W[(size_t)(n0 + lr) * K + k0 + lk];
    Xs[lk + 0][lr] = xv.x; Xs[lk + 1][lr] = xv.y;
    Xs[lk + 2][lr] = xv.z; Xs[lk + 3][lr] = xv.w;
    Ws[lk + 0][lr] = wv.x; Ws[lk + 1][lr] = wv.y;
    Ws[lk + 2][lr] = wv.z; Ws[lk + 3][lr] = wv.w;
    __syncthreads();
#pragma unroll
    for (int kk = 0; kk < 16; ++kk) {
      float4 a = *(const float4*)&Xs[kk][ty * 4];
      float4 b = *(const float4*)&Ws[kk][tx * 4];
      fma4x4(acc, a, b);
    }
  }

#pragma unroll
  for (int i = 0; i < 4; ++i) {
    int m = m0 + ty * 4 + i;
    int nb = n0 + tx * 4;
    float4 o;
    o.x = acc[i][0] + bias[nb + 0];
    o.y = acc[i][1] + bias[nb + 1];
    o.z = acc[i][2] + bias[nb + 2];
    o.w = acc[i][3] + bias[nb + 3];
    if (headmajor) {
      int b = m >> 11, s = m & (S_LEN - 1);
      int h = nb >> 6, d = nb & (HDIM - 1);
      *(float4*)&Y[(((size_t)(b * NHEAD + h)) * S_LEN + s) * HDIM + d] = o;
    } else {
      *(float4*)&Y[(size_t)m * N + nb] = o;
    }
  }
}

// gram[bh][i][j] = sum_s K[bh][s][i] * K[bh][s][j].  One block per (b,h).
__global__ __launch_bounds__(256) void gram_kernel(
    const float* __restrict__ Kh, float* __restrict__ gram)
{
  __shared__ __align__(16) float Ks[32][64];
  const int bh = blockIdx.x;
  const float* Kb = Kh + (size_t)bh * S_LEN * HDIM;
  const int tx = threadIdx.x & 15;
  const int ty = threadIdx.x >> 4;
  const int lr = threadIdx.x >> 3;          // 0..31
  const int lc = (threadIdx.x & 7) * 8;     // 0,8,..,56
  float acc[4][4] = {};

  for (int s0 = 0; s0 < S_LEN; s0 += 32) {
    __syncthreads();
    float4 v0 = *(const float4*)&Kb[(size_t)(s0 + lr) * HDIM + lc];
    float4 v1 = *(const float4*)&Kb[(size_t)(s0 + lr) * HDIM + lc + 4];
    *(float4*)&Ks[lr][lc] = v0;
    *(float4*)&Ks[lr][lc + 4] = v1;
    __syncthreads();
#pragma unroll
    for (int ss = 0; ss < 32; ++ss) {
      float4 a = *(const float4*)&Ks[ss][ty * 4];
      float4 b = *(const float4*)&Ks[ss][tx * 4];
      fma4x4(acc, a, b);
    }
  }
  float* G = gram + (size_t)bh * HDIM * HDIM;
#pragma unroll
  for (int i = 0; i < 4; ++i)
#pragma unroll
    for (int j = 0; j < 4; ++j)
      G[(ty * 4 + i) * HDIM + tx * 4 + j] = acc[i][j];
}

// Gauss-Jordan inverse of 64x64 SPD, no pivoting (gram ~ 2048*I, diag-dominant).
__global__ __launch_bounds__(256) void inv_kernel(
    const float* __restrict__ gram, float* __restrict__ ginv)
{
  __shared__ float aug[64][130];
  __shared__ float spiv;
  const int bh = blockIdx.x;
  const int t = threadIdx.x;
  const int r = t >> 2;             // 0..63: owned row
  const int c0 = (t & 3) * 32;      // 0,32,64,96: owned 32-col segment
  const float* G = gram + (size_t)bh * HDIM * HDIM;

  for (int cc = 0; cc < 32; ++cc) {
    int c = c0 + cc;
    aug[r][c] = (c < 64) ? G[r * 64 + c] : ((c - 64 == r) ? 1.0f : 0.0f);
  }
  __syncthreads();

  for (int k = 0; k < 64; ++k) {
    if (t == 0) spiv = 1.0f / aug[k][k];
    __syncthreads();
    if (r == k) {
      float p = spiv;
      for (int cc = 0; cc < 32; ++cc) aug[k][c0 + cc] *= p;
    }
    __syncthreads();
    if (r != k) {
      float f = aug[r][k];
      for (int cc = 0; cc < 32; ++cc)
        aug[r][c0 + cc] = fmaf(-f, aug[k][c0 + cc], aug[r][c0 + cc]);
    }
    __syncthreads();
  }

  float* O = ginv + (size_t)bh * HDIM * HDIM;
  if (c0 >= 64)
    for (int cc = 0; cc < 32; ++cc)
      O[r * 64 + (c0 - 64) + cc] = aug[r][c0 + cc];
}

// Fused: Qp = Q_tile @ Ginv; then streaming softmax(Qp K^T / 32) @ V.
// No max-subtraction needed: |score| <= ||G^-1/2 q||*||G^-1/2 k|| ~ 0.2 (Cauchy-Schwarz,
// since k_t k_t^T <= G), so exp() cannot overflow.
// Output written to AO[b][s][h*64+d] (the 0213 transpose is free here).
__global__ __launch_bounds__(256) void flash_kernel(
    const float* __restrict__ Qh, const float* __restrict__ Kh,
    const float* __restrict__ Vh, const float* __restrict__ Ginv,
    float* __restrict__ AO)
{
  struct P0 { float G[64][64]; float QinT[64][64]; };
  struct P1 { float KV[64][64]; float PT[64][64]; float lsum[64]; };
  union Smem { P0 p0; P1 p1; };
  __shared__ __align__(16) float QpT[64][64];   // [d][row]
  __shared__ __align__(16) Smem u;

  const int qt = blockIdx.x;        // q-tile 0..31
  const int bh = blockIdx.y;        // 0..31
  const int b = bh >> 4, h = bh & (NHEAD - 1);
  const float* Qb = Qh + (size_t)bh * S_LEN * HDIM;
  const float* Kb = Kh + (size_t)bh * S_LEN * HDIM;
  const float* Vb = Vh + (size_t)bh * S_LEN * HDIM;
  const int tx = threadIdx.x & 15;
  const int ty = threadIdx.x >> 4;
  const int lr = threadIdx.x >> 2;        // 0..63
  const int lc = (threadIdx.x & 3) * 16;  // 0,16,32,48

  // ---- phase 0: load Ginv (direct) + Q tile (transposed), compute QpT ----
#pragma unroll
  for (int i = 0; i < 4; ++i) {
    int cc = lc + i * 4;
    *(float4*)&u.p0.G[lr][cc] = *(const float4*)&Ginv[(size_t)bh * 4096 + lr * 64 + cc];
  }
#pragma unroll
  for (int i = 0; i < 4; ++i) {
    int d0 = lc + i * 4;
    float4 v = *(const float4*)&Qb[(size_t)(qt * 64 + lr) * HDIM + d0];
    u.p0.QinT[d0 + 0][lr] = v.x; u.p0.QinT[d0 + 1][lr] = v.y;
    u.p0.QinT[d0 + 2][lr] = v.z; u.p0.QinT[d0 + 3][lr] = v.w;
  }
  if (threadIdx.x < 64) u.p1.lsum[threadIdx.x] = 0.0f;  // lsum is beyond p0's extent
  __syncthreads();

  {
    float qp[4][4] = {};
#pragma unroll 8
    for (int kk = 0; kk < 64; ++kk) {
      float4 a = *(const float4*)&u.p0.QinT[kk][ty * 4];
      float4 g = *(const float4*)&u.p0.G[kk][tx * 4];
      fma4x4(qp, a, g);
    }
    // QpT[d][row] so the QK^T loop can float4 over rows
#pragma unroll
    for (int i = 0; i < 4; ++i)
#pragma unroll
      for (int j = 0; j < 4; ++j)
        QpT[tx * 4 + j][ty * 4 + i] = qp[i][j];
  }
  __syncthreads();   // QpT visible; p0 reads done before KV overwrite

  // ---- flash loop over 32 key tiles ----
  float acc[4][4] = {};
  const float scale = 0.03125f;  // 1/sqrt(1024)
  for (int kt = 0; kt < 32; ++kt) {
    // stage K tile transposed: KV[d][key]
#pragma unroll
    for (int i = 0; i < 4; ++i) {
      int d0 = lc + i * 4;
      float4 v = *(const float4*)&Kb[(size_t)(kt * 64 + lr) * HDIM + d0];
      u.p1.KV[d0 + 0][lr] = v.x; u.p1.KV[d0 + 1][lr] = v.y;
      u.p1.KV[d0 + 2][lr] = v.z; u.p1.KV[d0 + 3][lr] = v.w;
    }
    __syncthreads();

    float pv[4][4];
    {
      float s[4][4] = {};
#pragma unroll 8
      for (int kk = 0; kk < 64; ++kk) {
        float4 a = *(const float4*)&QpT[kk][ty * 4];
        float4 kkv = *(const float4*)&u.p1.KV[kk][tx * 4];
        fma4x4(s, a, kkv);
      }
#pragma unroll
      for (int i = 0; i < 4; ++i)
#pragma unroll
        for (int j = 0; j < 4; ++j)
          pv[i][j] = __expf(s[i][j] * scale);
    }
    __syncthreads();  // done reading K from KV

    // stage V tile direct: KV[key][d]; write PT[key][row]
#pragma unroll
    for (int i = 0; i < 4; ++i) {
      int c0 = lc + i * 4;
      *(float4*)&u.p1.KV[lr][c0] = *(const float4*)&Vb[(size_t)(kt * 64 + lr) * HDIM + c0];
    }
#pragma unroll
    for (int i = 0; i < 4; ++i)
#pragma unroll
      for (int j = 0; j < 4; ++j)
        u.p1.PT[tx * 4 + j][ty * 4 + i] = pv[i][j];
    __syncthreads();

    // acc += P @ V ; lsum += rowsum(P)
#pragma unroll 8
    for (int kk = 0; kk < 64; ++kk) {
      float4 a = *(const float4*)&u.p1.PT[kk][ty * 4];
      float4 vv = *(const float4*)&u.p1.KV[kk][tx * 4];
      fma4x4(acc, a, vv);
    }
    if (threadIdx.x < 64) {
      float ssum = 0.0f;
      for (int kk = 0; kk < 64; ++kk) ssum += u.p1.PT[kk][threadIdx.x];
      u.p1.lsum[threadIdx.x] += ssum;
    }
    __syncthreads();
  }

  // ---- epilogue: divide by lsum, write AO[b][s][h*64+d] ----
  float* AOb = AO + (size_t)b * S_LEN * EMB + h * HDIM;
#pragma unroll
  for (int i = 0; i < 4; ++i) {
    int r = ty * 4 + i;
    float inv_l = 1.0f / u.p1.lsum[r];
    float4 o;
    o.x = acc[i][0] * inv_l;
    o.y = acc[i][1] * inv_l;
    o.z = acc[i][2] * inv_l;
    o.w = acc[i][3] * inv_l;
    *(float4*)&AOb[(size_t)(qt * 64 + r) * EMB + tx * 4] = o;
  }
}

extern "C" void kernel_launch(void* const* d_in, const int* in_sizes, int n_in,
                              void* d_out, int out_size, void* d_ws, size_t ws_size,
                              hipStream_t stream) {
  (void)in_sizes; (void)n_in; (void)out_size; (void)ws_size;
  const float* x   = (const float*)d_in[0];
  const float* Wq  = (const float*)d_in[1];
  const float* bq  = (const float*)d_in[2];
  const float* Wk  = (const float*)d_in[3];
  const float* bk  = (const float*)d_in[4];
  const float* Wv  = (const float*)d_in[5];
  const float* bv  = (const float*)d_in[6];
  const float* Wfc = (const float*)d_in[7];
  const float* bfc = (const float*)d_in[8];
  float* out = (float*)d_out;

  float* ws = (float*)d_ws;
  float* Qh   = ws;                          // [2,16,2048,64] = 4M floats
  float* Kh   = ws + (size_t)4 * 1024 * 1024;
  float* Vh   = ws + (size_t)8 * 1024 * 1024;
  float* AO   = ws + (size_t)12 * 1024 * 1024;  // [2,2048,1024]
  float* gram = ws + (size_t)16 * 1024 * 1024;  // 32*64*64
  float* ginv = gram + 32 * 64 * 64;

  dim3 gB(EMB / 64, MROWS / 64);  // (16, 64)
  gemm_bt_f32<<<gB, 256, 0, stream>>>(x, Wq, bq, Qh, MROWS, EMB, EMB, 1);
  gemm_bt_f32<<<gB, 256, 0, stream>>>(x, Wk, bk, Kh, MROWS, EMB, EMB, 1);
  gemm_bt_f32<<<gB, 256, 0, stream>>>(x, Wv, bv, Vh, MROWS, EMB, EMB, 1);
  gram_kernel<<<32, 256, 0, stream>>>(Kh, gram);
  inv_kernel<<<32, 256, 0, stream>>>(gram, ginv);
  flash_kernel<<<dim3(S_LEN / 64, 32), 256, 0, stream>>>(Qh, Kh, Vh, ginv, AO);
  gemm_bt_f32<<<gB, 256, 0, stream>>>(AO, Wfc, bfc, out, MROWS, EMB, EMB, 0);
}

// Round 2
// 389.756 us; speedup vs baseline: 3.1645x; 3.1645x over previous
//
#include <hip/hip_runtime.h>
#include <cstddef>
#include <cstdint>

#define S_LEN 2048
#define NHEAD 16
#define HDIM  64
#define EMB   1024
#define MROWS 4096

typedef short bf16x8 __attribute__((ext_vector_type(8)));
typedef float f32x4 __attribute__((ext_vector_type(4)));

__device__ __forceinline__ unsigned short f2bf(float f) {
  union { float f; unsigned u; } v; v.f = f;
  unsigned r = v.u + 0x7FFF + ((v.u >> 16) & 1);
  return (unsigned short)(r >> 16);
}

__device__ __forceinline__ f32x4 fzero() {
  f32x4 z = {0.0f, 0.0f, 0.0f, 0.0f};
  return z;
}

// Cast x (4M), Wq,Wk,Wv,Wfc (1M each) fp32 -> bf16, contiguous dst.
__global__ __launch_bounds__(256) void cast_kernel(
    const float* __restrict__ x, const float* __restrict__ Wq,
    const float* __restrict__ Wk, const float* __restrict__ Wv,
    const float* __restrict__ Wfc, unsigned short* __restrict__ dst)
{
  size_t idx8 = (size_t)(blockIdx.x * 256 + threadIdx.x) * 8;
  unsigned seg = (unsigned)(idx8 >> 20);
  const float* src;
  size_t off;
  if (seg < 4) { src = x; off = idx8; }
  else {
    const float* w4[4] = {Wq, Wk, Wv, Wfc};
    src = w4[seg - 4];
    off = idx8 & 0xFFFFFu;
  }
  float4 a = *(const float4*)&src[off];
  float4 b = *(const float4*)&src[off + 4];
  union { unsigned short h[8]; uint4 u; } p;
  p.h[0] = f2bf(a.x); p.h[1] = f2bf(a.y); p.h[2] = f2bf(a.z); p.h[3] = f2bf(a.w);
  p.h[4] = f2bf(b.x); p.h[5] = f2bf(b.y); p.h[6] = f2bf(b.z); p.h[7] = f2bf(b.w);
  *(uint4*)&dst[idx8] = p.u;
}

// Y = A @ B^T + bias. A:[M,K] bf16 rm, B:[N,K] bf16 rm. 128x128 tile, BK=32.
// mode 0: Yf fp32 [M][N]
// mode 1: Yh bf16 head-major [b*16+h][s][d]
// mode 2: mode1 + Yt bf16 transposed [b*16+h][d][s]
// mode 3: Yt only
__global__ __launch_bounds__(256) void gemm_mfma(
    const unsigned short* __restrict__ A, const unsigned short* __restrict__ B,
    const float* __restrict__ bias, float* __restrict__ Yf,
    unsigned short* __restrict__ Yh, unsigned short* __restrict__ Yt,
    int M, int N, int K, int mode)
{
  __shared__ short As[128][40];   // +8 pad: row stride 80B -> conflict-free b128 frags
  __shared__ short Bs[128][40];
  const int t = threadIdx.x;
  const int lane = t & 63, w = t >> 6;
  const int quad = lane >> 4, l16 = lane & 15;
  const int wr = w >> 1, wc = w & 1;
  const int m0 = blockIdx.y * 128, n0 = blockIdx.x * 128;
  const int sr = t >> 2, sk = (t & 3) * 8;

  f32x4 acc[4][4];
#pragma unroll
  for (int i = 0; i < 4; ++i)
#pragma unroll
    for (int j = 0; j < 4; ++j) acc[i][j] = fzero();

  // prefetch k0=0
  float4 pa0 = *(const float4*)&A[(size_t)(m0 + sr) * K + sk];
  float4 pa1 = *(const float4*)&A[(size_t)(m0 + 64 + sr) * K + sk];
  float4 pb0 = *(const float4*)&B[(size_t)(n0 + sr) * K + sk];
  float4 pb1 = *(const float4*)&B[(size_t)(n0 + 64 + sr) * K + sk];

  for (int k0 = 0; k0 < K; k0 += 32) {
    __syncthreads();
    *(float4*)&As[sr][sk] = pa0;
    *(float4*)&As[64 + sr][sk] = pa1;
    *(float4*)&Bs[sr][sk] = pb0;
    *(float4*)&Bs[64 + sr][sk] = pb1;
    __syncthreads();
    if (k0 + 32 < K) {
      pa0 = *(const float4*)&A[(size_t)(m0 + sr) * K + k0 + 32 + sk];
      pa1 = *(const float4*)&A[(size_t)(m0 + 64 + sr) * K + k0 + 32 + sk];
      pb0 = *(const float4*)&B[(size_t)(n0 + sr) * K + k0 + 32 + sk];
      pb1 = *(const float4*)&B[(size_t)(n0 + 64 + sr) * K + k0 + 32 + sk];
    }
    bf16x8 af[4], bfr[4];
#pragma unroll
    for (int i = 0; i < 4; ++i)
      af[i] = *(const bf16x8*)&As[64 * wr + 16 * i + l16][quad * 8];
#pragma unroll
    for (int j = 0; j < 4; ++j)
      bfr[j] = *(const bf16x8*)&Bs[64 * wc + 16 * j + l16][quad * 8];
#pragma unroll
    for (int i = 0; i < 4; ++i)
#pragma unroll
      for (int j = 0; j < 4; ++j)
        acc[i][j] = __builtin_amdgcn_mfma_f32_16x16x32_bf16(af[i], bfr[j], acc[i][j], 0, 0, 0);
  }

  // epilogue. C layout: col = l16 (n), row = quad*4+reg (m)
#pragma unroll
  for (int i = 0; i < 4; ++i) {
    int mb = m0 + 64 * wr + 16 * i + quad * 4;
#pragma unroll
    for (int j = 0; j < 4; ++j) {
      int n = n0 + 64 * wc + 16 * j + l16;
      float bv = bias[n];
      if (mode == 0) {
#pragma unroll
        for (int r = 0; r < 4; ++r)
          Yf[(size_t)(mb + r) * N + n] = acc[i][j][r] + bv;
      } else {
        int h = n >> 6, d = n & 63;
        if (mode != 3) {
#pragma unroll
          for (int r = 0; r < 4; ++r) {
            int m = mb + r;
            int b = m >> 11, s = m & 2047;
            Yh[((size_t)(b * NHEAD + h)) * 131072 + (size_t)s * 64 + d] =
                f2bf(acc[i][j][r] + bv);
          }
        }
        if (mode >= 2) {
          int b = mb >> 11, s = mb & 2047;  // 4 consecutive s, same b
          unsigned short h0 = f2bf(acc[i][j][0] + bv);
          unsigned short h1 = f2bf(acc[i][j][1] + bv);
          unsigned short h2 = f2bf(acc[i][j][2] + bv);
          unsigned short h3 = f2bf(acc[i][j][3] + bv);
          uint2 pk;
          pk.x = (unsigned)h0 | ((unsigned)h1 << 16);
          pk.y = (unsigned)h2 | ((unsigned)h3 << 16);
          *(uint2*)&Yt[((size_t)(b * NHEAD + h)) * 131072 + (size_t)d * S_LEN + s] = pk;
        }
      }
    }
  }
}

// gram[bh] = K^T K from KT [bh][d][s] bf16, fp32 out. One block per bh.
__global__ __launch_bounds__(256) void gram_mfma(
    const unsigned short* __restrict__ KTh, float* __restrict__ gram)
{
  __shared__ short KTs[64][136];
  const int t = threadIdx.x;
  const int lane = t & 63, w = t >> 6;
  const int quad = lane >> 4, l16 = lane & 15;
  const int bh = blockIdx.x;
  const unsigned short* Kb = KTh + (size_t)bh * 131072;

  f32x4 gacc[4];
#pragma unroll
  for (int j = 0; j < 4; ++j) gacc[j] = fzero();

  const int rv = t >> 4, cv = (t & 15) * 8;
  for (int st = 0; st < 16; ++st) {
    float4 vv[4];
#pragma unroll
    for (int r = 0; r < 4; ++r)
      vv[r] = *(const float4*)&Kb[(size_t)(rv + 16 * r) * S_LEN + st * 128 + cv];
    __syncthreads();
#pragma unroll
    for (int r = 0; r < 4; ++r)
      *(float4*)&KTs[rv + 16 * r][cv] = vv[r];
    __syncthreads();
#pragma unroll
    for (int c = 0; c < 4; ++c) {
      bf16x8 ai = *(const bf16x8*)&KTs[16 * w + l16][32 * c + quad * 8];
#pragma unroll
      for (int jb = 0; jb < 4; ++jb) {
        bf16x8 bj = *(const bf16x8*)&KTs[16 * jb + l16][32 * c + quad * 8];
        gacc[jb] = __builtin_amdgcn_mfma_f32_16x16x32_bf16(ai, bj, gacc[jb], 0, 0, 0);
      }
    }
  }
#pragma unroll
  for (int jb = 0; jb < 4; ++jb)
#pragma unroll
    for (int r = 0; r < 4; ++r)
      gram[(size_t)bh * 4096 + (size_t)(16 * w + quad * 4 + r) * 64 + 16 * jb + l16] =
          gacc[jb][r];
}

// Gauss-Jordan inverse of 64x64 SPD (diag-dominant, no pivoting). bf16 out.
__global__ __launch_bounds__(256) void inv_kernel(
    const float* __restrict__ gram, unsigned short* __restrict__ ginv)
{
  __shared__ float aug[64][130];
  __shared__ float spiv;
  const int bh = blockIdx.x;
  const int t = threadIdx.x;
  const int r = t >> 2;
  const int c0 = (t & 3) * 32;
  const float* G = gram + (size_t)bh * 4096;

  for (int cc = 0; cc < 32; ++cc) {
    int c = c0 + cc;
    aug[r][c] = (c < 64) ? G[r * 64 + c] : ((c - 64 == r) ? 1.0f : 0.0f);
  }
  __syncthreads();

  for (int k = 0; k < 64; ++k) {
    if (t == 0) spiv = 1.0f / aug[k][k];
    __syncthreads();
    if (r == k) {
      float p = spiv;
      for (int cc = 0; cc < 32; ++cc) aug[k][c0 + cc] *= p;
    }
    __syncthreads();
    if (r != k) {
      float f = aug[r][k];
      for (int cc = 0; cc < 32; ++cc)
        aug[r][c0 + cc] = fmaf(-f, aug[k][c0 + cc], aug[r][c0 + cc]);
    }
    __syncthreads();
  }

  unsigned short* O = ginv + (size_t)bh * 4096;
  if (c0 >= 64)
    for (int cc = 0; cc < 32; ++cc)
      O[r * 64 + (c0 - 64) + cc] = f2bf(aug[r][c0 + cc]);
}

// Fused flash: Qp = Q@Ginv; S^T = K@Qp^T; P=exp(S/32); O = P@V / rowsum.
// Q,K: [bh][s][d] bf16; VT: [bh][d][s] bf16; Ginv: [bh][64][64] bf16 (symmetric).
// AO out: [b][s][h*64+d] bf16.
__global__ __launch_bounds__(256) void flash_mfma(
    const unsigned short* __restrict__ Qh, const unsigned short* __restrict__ Kh,
    const unsigned short* __restrict__ VTh, const unsigned short* __restrict__ Ginv,
    unsigned short* __restrict__ AO)
{
  __shared__ short Ks[128][72];
  __shared__ short VTs[64][136];
  __shared__ short Ps[64][136];
  __shared__ short Qps[64][72];
  __shared__ float Lred[4][64];
  const int t = threadIdx.x;
  const int lane = t & 63, w = t >> 6;
  const int quad = lane >> 4, l16 = lane & 15;
  const int qt = blockIdx.x, bh = blockIdx.y;
  const unsigned short* Qb = Qh + (size_t)bh * 131072;
  const unsigned short* Kb = Kh + (size_t)bh * 131072;
  const unsigned short* Vb = VTh + (size_t)bh * 131072;
  short* G0 = &VTs[0][0];  // Ginv staged with stride 72 inside VTs

  // ---- phase 0: stage Q (into Ks rows 0..63) + Ginv; compute Qp -> Qps ----
  {
    int r0 = t >> 3, cq = (t & 7) * 8;
#pragma unroll
    for (int r = 0; r < 2; ++r) {
      int row = r0 + 32 * r;
      *(float4*)&Ks[row][cq] = *(const float4*)&Qb[(size_t)(qt * 64 + row) * 64 + cq];
      *(float4*)&G0[row * 72 + cq] = *(const float4*)&Ginv[(size_t)bh * 4096 + row * 64 + cq];
    }
  }
  __syncthreads();
  {
    f32x4 qacc[4];
#pragma unroll
    for (int nb = 0; nb < 4; ++nb) qacc[nb] = fzero();
#pragma unroll
    for (int c = 0; c < 2; ++c) {
      bf16x8 aq = *(const bf16x8*)&Ks[16 * w + l16][32 * c + quad * 8];
#pragma unroll
      for (int nb = 0; nb < 4; ++nb) {
        bf16x8 bg = *(const bf16x8*)&G0[(16 * nb + l16) * 72 + 32 * c + quad * 8];
        qacc[nb] = __builtin_amdgcn_mfma_f32_16x16x32_bf16(aq, bg, qacc[nb], 0, 0, 0);
      }
    }
    __syncthreads();  // Q/G reads done before Ks/VTs reuse; Qps writes next
#pragma unroll
    for (int nb = 0; nb < 4; ++nb)
#pragma unroll
      for (int r = 0; r < 4; ++r)
        Qps[16 * w + quad * 4 + r][16 * nb + l16] = f2bf(qacc[nb][r]);
  }
  float lsum[4] = {0.0f, 0.0f, 0.0f, 0.0f};
  f32x4 oacc[4];
#pragma unroll
  for (int db = 0; db < 4; ++db) oacc[db] = fzero();
  __syncthreads();  // Qps visible to all waves

  const float scale = 0.03125f;  // 1/sqrt(1024)
  const int rk = t >> 3, ck = (t & 7) * 8;
  const int rv = t >> 4, cv = (t & 15) * 8;

  for (int kt = 0; kt < 16; ++kt) {
    // stage K [128][64] and VT [64][128]
    float4 kv[4], vv[4];
#pragma unroll
    for (int r = 0; r < 4; ++r)
      kv[r] = *(const float4*)&Kb[(size_t)(kt * 128 + rk + 32 * r) * 64 + ck];
#pragma unroll
    for (int r = 0; r < 4; ++r)
      vv[r] = *(const float4*)&Vb[(size_t)(rv + 16 * r) * S_LEN + kt * 128 + cv];
#pragma unroll
    for (int r = 0; r < 4; ++r) *(float4*)&Ks[rk + 32 * r][ck] = kv[r];
#pragma unroll
    for (int r = 0; r < 4; ++r) *(float4*)&VTs[rv + 16 * r][cv] = vv[r];
    __syncthreads();

    // S^T = K @ Qp^T : wave w owns keys [32w, 32w+32)
    f32x4 sacc[2][4];
#pragma unroll
    for (int kb = 0; kb < 2; ++kb)
#pragma unroll
      for (int qb = 0; qb < 4; ++qb) sacc[kb][qb] = fzero();
#pragma unroll
    for (int c = 0; c < 2; ++c) {
      bf16x8 ak0 = *(const bf16x8*)&Ks[32 * w + l16][32 * c + quad * 8];
      bf16x8 ak1 = *(const bf16x8*)&Ks[32 * w + 16 + l16][32 * c + quad * 8];
#pragma unroll
      for (int qb = 0; qb < 4; ++qb) {
        bf16x8 bq = *(const bf16x8*)&Qps[16 * qb + l16][32 * c + quad * 8];
        sacc[0][qb] = __builtin_amdgcn_mfma_f32_16x16x32_bf16(ak0, bq, sacc[0][qb], 0, 0, 0);
        sacc[1][qb] = __builtin_amdgcn_mfma_f32_16x16x32_bf16(ak1, bq, sacc[1][qb], 0, 0, 0);
      }
    }
    // exp -> lsum partials -> packed P^T write (4 consecutive keys per lane)
#pragma unroll
    for (int kb = 0; kb < 2; ++kb)
#pragma unroll
      for (int qb = 0; qb < 4; ++qb) {
        float e0 = __expf(sacc[kb][qb][0] * scale);
        float e1 = __expf(sacc[kb][qb][1] * scale);
        float e2 = __expf(sacc[kb][qb][2] * scale);
        float e3 = __expf(sacc[kb][qb][3] * scale);
        lsum[qb] += (e0 + e1) + (e2 + e3);
        uint2 pk;
        pk.x = (unsigned)f2bf(e0) | ((unsigned)f2bf(e1) << 16);
        pk.y = (unsigned)f2bf(e2) | ((unsigned)f2bf(e3) << 16);
        *(uint2*)&Ps[16 * qb + l16][32 * w + 16 * kb + quad * 4] = pk;
      }
    __syncthreads();

    // O += P @ V : wave w owns q rows [16w, 16w+16)
#pragma unroll
    for (int c = 0; c < 4; ++c) {
      bf16x8 ap = *(const bf16x8*)&Ps[16 * w + l16][32 * c + quad * 8];
#pragma unroll
      for (int db = 0; db < 4; ++db) {
        bf16x8 bv = *(const bf16x8*)&VTs[16 * db + l16][32 * c + quad * 8];
        oacc[db] = __builtin_amdgcn_mfma_f32_16x16x32_bf16(ap, bv, oacc[db], 0, 0, 0);
      }
    }
    __syncthreads();  // PV reads done before next staging
  }

  // ---- softmax denominator: quad-butterfly + cross-wave via LDS ----
#pragma unroll
  for (int qb = 0; qb < 4; ++qb) {
    lsum[qb] += __shfl_xor(lsum[qb], 16, 64);
    lsum[qb] += __shfl_xor(lsum[qb], 32, 64);
  }
  if (lane < 16)
#pragma unroll
    for (int qb = 0; qb < 4; ++qb) Lred[w][qb * 16 + l16] = lsum[qb];
  __syncthreads();
  if (t < 64)
    Lred[0][t] = 1.0f / (Lred[0][t] + Lred[1][t] + Lred[2][t] + Lred[3][t]);
  __syncthreads();

  const int b = bh >> 4, h = bh & 15;
#pragma unroll
  for (int r = 0; r < 4; ++r) {
    int q = 16 * w + quad * 4 + r;
    float li = Lred[0][q];
    int s = qt * 64 + q;
    size_t base = (size_t)b * S_LEN * EMB + (size_t)s * EMB + h * 64;
#pragma unroll
    for (int db = 0; db < 4; ++db)
      AO[base + 16 * db + l16] = f2bf(oacc[db][r] * li);
  }
}

extern "C" void kernel_launch(void* const* d_in, const int* in_sizes, int n_in,
                              void* d_out, int out_size, void* d_ws, size_t ws_size,
                              hipStream_t stream) {
  (void)in_sizes; (void)n_in; (void)out_size; (void)ws_size;
  const float* x   = (const float*)d_in[0];
  const float* Wq  = (const float*)d_in[1];
  const float* bq  = (const float*)d_in[2];
  const float* Wk  = (const float*)d_in[3];
  const float* bk  = (const float*)d_in[4];
  const float* Wv  = (const float*)d_in[5];
  const float* bv  = (const float*)d_in[6];
  const float* Wfc = (const float*)d_in[7];
  const float* bfc = (const float*)d_in[8];
  float* out = (float*)d_out;

  unsigned short* xb   = (unsigned short*)d_ws;            // [4096][1024]
  unsigned short* Wqb  = xb + (size_t)4194304;
  unsigned short* Wkb  = Wqb + 1048576;
  unsigned short* Wvb  = Wkb + 1048576;
  unsigned short* Wfcb = Wvb + 1048576;
  unsigned short* Qhd  = Wfcb + 1048576;                   // [32][2048][64]
  unsigned short* Khd  = Qhd + 4194304;
  unsigned short* KTd  = Khd + 4194304;                    // [32][64][2048]
  unsigned short* VTd  = KTd + 4194304;                    // [32][64][2048]
  unsigned short* AOd  = VTd + 4194304;                    // [2][2048][1024]
  float* gram          = (float*)(AOd + 4194304);          // [32][64][64] f32
  unsigned short* ginv = (unsigned short*)(gram + 131072); // [32][64][64] bf16

  cast_kernel<<<4096, 256, 0, stream>>>(x, Wq, Wk, Wv, Wfc, xb);
  dim3 g(EMB / 128, MROWS / 128);  // (8, 32)
  gemm_mfma<<<g, 256, 0, stream>>>(xb, Wqb, bq, nullptr, Qhd, nullptr, MROWS, EMB, EMB, 1);
  gemm_mfma<<<g, 256, 0, stream>>>(xb, Wkb, bk, nullptr, Khd, KTd, MROWS, EMB, EMB, 2);
  gemm_mfma<<<g, 256, 0, stream>>>(xb, Wvb, bv, nullptr, nullptr, VTd, MROWS, EMB, EMB, 3);
  gram_mfma<<<32, 256, 0, stream>>>(KTd, gram);
  inv_kernel<<<32, 256, 0, stream>>>(gram, ginv);
  flash_mfma<<<dim3(S_LEN / 64, 32), 256, 0, stream>>>(Qhd, Khd, VTd, ginv, AOd);
  gemm_mfma<<<g, 256, 0, stream>>>(AOd, Wfcb, bfc, out, nullptr, nullptr, MROWS, EMB, EMB, 0);
}

// Round 3
// 298.679 us; speedup vs baseline: 4.1294x; 1.3049x over previous
//
#include <hip/hip_runtime.h>
#include <cstddef>
#include <cstdint>

#define S_LEN 2048
#define NHEAD 16
#define HDIM  64
#define EMB   1024
#define MROWS 4096

typedef short bf16x8 __attribute__((ext_vector_type(8)));
typedef float f32x4 __attribute__((ext_vector_type(4)));

__device__ __forceinline__ unsigned short f2bf(float f) {
  union { float f; unsigned u; } v; v.f = f;
  unsigned r = v.u + 0x7FFF + ((v.u >> 16) & 1);
  return (unsigned short)(r >> 16);
}

__device__ __forceinline__ f32x4 fzero() {
  f32x4 z = {0.0f, 0.0f, 0.0f, 0.0f};
  return z;
}

// Cast x (4M), Wq,Wk,Wv,Wfc (1M each) fp32 -> bf16, contiguous dst.
__global__ __launch_bounds__(256) void cast_kernel(
    const float* __restrict__ x, const float* __restrict__ Wq,
    const float* __restrict__ Wk, const float* __restrict__ Wv,
    const float* __restrict__ Wfc, unsigned short* __restrict__ dst)
{
  size_t idx8 = (size_t)(blockIdx.x * 256 + threadIdx.x) * 8;
  unsigned seg = (unsigned)(idx8 >> 20);
  const float* src;
  size_t off;
  if (seg < 4) { src = x; off = idx8; }
  else {
    const float* w4[4] = {Wq, Wk, Wv, Wfc};
    src = w4[seg - 4];
    off = idx8 & 0xFFFFFu;
  }
  float4 a = *(const float4*)&src[off];
  float4 b = *(const float4*)&src[off + 4];
  union { unsigned short h[8]; uint4 u; } p;
  p.h[0] = f2bf(a.x); p.h[1] = f2bf(a.y); p.h[2] = f2bf(a.z); p.h[3] = f2bf(a.w);
  p.h[4] = f2bf(b.x); p.h[5] = f2bf(b.y); p.h[6] = f2bf(b.z); p.h[7] = f2bf(b.w);
  *(uint4*)&dst[idx8] = p.u;
}

// QKV fused: z = blockIdx.z selects weight/bias/output set.
// Y = x @ W^T + bias, 128x128 tile, BK=32.
// z=0: Qhd [bh][s][d]; z=1: Khd [bh][s][d] + KTd [bh][d][s]; z=2: VTd [bh][d][s].
__global__ __launch_bounds__(256) void gemm_qkv(
    const unsigned short* __restrict__ A, const unsigned short* __restrict__ Wall,
    const float* __restrict__ bq, const float* __restrict__ bk,
    const float* __restrict__ bv, unsigned short* __restrict__ Qhd,
    unsigned short* __restrict__ Khd, unsigned short* __restrict__ KTd,
    unsigned short* __restrict__ VTd)
{
  __shared__ short As[128][40];
  __shared__ short Bs[128][40];
  const int z = blockIdx.z;
  const unsigned short* B = Wall + (size_t)z * 1048576;
  const float* bias = (z == 0) ? bq : (z == 1) ? bk : bv;
  unsigned short* Yh = (z == 0) ? Qhd : (z == 1) ? Khd : nullptr;
  unsigned short* Yt = (z == 1) ? KTd : (z == 2) ? VTd : nullptr;
  const int K = EMB;
  const int t = threadIdx.x;
  const int lane = t & 63, w = t >> 6;
  const int quad = lane >> 4, l16 = lane & 15;
  const int wr = w >> 1, wc = w & 1;
  const int m0 = blockIdx.y * 128, n0 = blockIdx.x * 128;
  const int sr = t >> 2, sk = (t & 3) * 8;

  f32x4 acc[4][4];
#pragma unroll
  for (int i = 0; i < 4; ++i)
#pragma unroll
    for (int j = 0; j < 4; ++j) acc[i][j] = fzero();

  float4 pa0 = *(const float4*)&A[(size_t)(m0 + sr) * K + sk];
  float4 pa1 = *(const float4*)&A[(size_t)(m0 + 64 + sr) * K + sk];
  float4 pb0 = *(const float4*)&B[(size_t)(n0 + sr) * K + sk];
  float4 pb1 = *(const float4*)&B[(size_t)(n0 + 64 + sr) * K + sk];

  for (int k0 = 0; k0 < K; k0 += 32) {
    __syncthreads();
    *(float4*)&As[sr][sk] = pa0;
    *(float4*)&As[64 + sr][sk] = pa1;
    *(float4*)&Bs[sr][sk] = pb0;
    *(float4*)&Bs[64 + sr][sk] = pb1;
    __syncthreads();
    if (k0 + 32 < K) {
      pa0 = *(const float4*)&A[(size_t)(m0 + sr) * K + k0 + 32 + sk];
      pa1 = *(const float4*)&A[(size_t)(m0 + 64 + sr) * K + k0 + 32 + sk];
      pb0 = *(const float4*)&B[(size_t)(n0 + sr) * K + k0 + 32 + sk];
      pb1 = *(const float4*)&B[(size_t)(n0 + 64 + sr) * K + k0 + 32 + sk];
    }
    bf16x8 af[4], bfr[4];
#pragma unroll
    for (int i = 0; i < 4; ++i)
      af[i] = *(const bf16x8*)&As[64 * wr + 16 * i + l16][quad * 8];
#pragma unroll
    for (int j = 0; j < 4; ++j)
      bfr[j] = *(const bf16x8*)&Bs[64 * wc + 16 * j + l16][quad * 8];
#pragma unroll
    for (int i = 0; i < 4; ++i)
#pragma unroll
      for (int j = 0; j < 4; ++j)
        acc[i][j] = __builtin_amdgcn_mfma_f32_16x16x32_bf16(af[i], bfr[j], acc[i][j], 0, 0, 0);
  }

#pragma unroll
  for (int i = 0; i < 4; ++i) {
    int mb = m0 + 64 * wr + 16 * i + quad * 4;
#pragma unroll
    for (int j = 0; j < 4; ++j) {
      int n = n0 + 64 * wc + 16 * j + l16;
      float bvv = bias[n];
      int h = n >> 6, d = n & 63;
      if (Yh) {
#pragma unroll
        for (int r = 0; r < 4; ++r) {
          int m = mb + r;
          int b = m >> 11, s = m & 2047;
          Yh[((size_t)(b * NHEAD + h)) * 131072 + (size_t)s * 64 + d] =
              f2bf(acc[i][j][r] + bvv);
        }
      }
      if (Yt) {
        int b = mb >> 11, s = mb & 2047;
        unsigned short h0 = f2bf(acc[i][j][0] + bvv);
        unsigned short h1 = f2bf(acc[i][j][1] + bvv);
        unsigned short h2 = f2bf(acc[i][j][2] + bvv);
        unsigned short h3 = f2bf(acc[i][j][3] + bvv);
        uint2 pk;
        pk.x = (unsigned)h0 | ((unsigned)h1 << 16);
        pk.y = (unsigned)h2 | ((unsigned)h3 << 16);
        *(uint2*)&Yt[((size_t)(b * NHEAD + h)) * 131072 + (size_t)d * S_LEN + s] = pk;
      }
    }
  }
}

// Final: out = AO @ Wfc^T + bfc, fp32 out [M][N].
__global__ __launch_bounds__(256) void gemm_fc(
    const unsigned short* __restrict__ A, const unsigned short* __restrict__ B,
    const float* __restrict__ bias, float* __restrict__ Yf)
{
  __shared__ short As[128][40];
  __shared__ short Bs[128][40];
  const int K = EMB, N = EMB;
  const int t = threadIdx.x;
  const int lane = t & 63, w = t >> 6;
  const int quad = lane >> 4, l16 = lane & 15;
  const int wr = w >> 1, wc = w & 1;
  const int m0 = blockIdx.y * 128, n0 = blockIdx.x * 128;
  const int sr = t >> 2, sk = (t & 3) * 8;

  f32x4 acc[4][4];
#pragma unroll
  for (int i = 0; i < 4; ++i)
#pragma unroll
    for (int j = 0; j < 4; ++j) acc[i][j] = fzero();

  float4 pa0 = *(const float4*)&A[(size_t)(m0 + sr) * K + sk];
  float4 pa1 = *(const float4*)&A[(size_t)(m0 + 64 + sr) * K + sk];
  float4 pb0 = *(const float4*)&B[(size_t)(n0 + sr) * K + sk];
  float4 pb1 = *(const float4*)&B[(size_t)(n0 + 64 + sr) * K + sk];

  for (int k0 = 0; k0 < K; k0 += 32) {
    __syncthreads();
    *(float4*)&As[sr][sk] = pa0;
    *(float4*)&As[64 + sr][sk] = pa1;
    *(float4*)&Bs[sr][sk] = pb0;
    *(float4*)&Bs[64 + sr][sk] = pb1;
    __syncthreads();
    if (k0 + 32 < K) {
      pa0 = *(const float4*)&A[(size_t)(m0 + sr) * K + k0 + 32 + sk];
      pa1 = *(const float4*)&A[(size_t)(m0 + 64 + sr) * K + k0 + 32 + sk];
      pb0 = *(const float4*)&B[(size_t)(n0 + sr) * K + k0 + 32 + sk];
      pb1 = *(const float4*)&B[(size_t)(n0 + 64 + sr) * K + k0 + 32 + sk];
    }
    bf16x8 af[4], bfr[4];
#pragma unroll
    for (int i = 0; i < 4; ++i)
      af[i] = *(const bf16x8*)&As[64 * wr + 16 * i + l16][quad * 8];
#pragma unroll
    for (int j = 0; j < 4; ++j)
      bfr[j] = *(const bf16x8*)&Bs[64 * wc + 16 * j + l16][quad * 8];
#pragma unroll
    for (int i = 0; i < 4; ++i)
#pragma unroll
      for (int j = 0; j < 4; ++j)
        acc[i][j] = __builtin_amdgcn_mfma_f32_16x16x32_bf16(af[i], bfr[j], acc[i][j], 0, 0, 0);
  }

#pragma unroll
  for (int i = 0; i < 4; ++i) {
    int mb = m0 + 64 * wr + 16 * i + quad * 4;
#pragma unroll
    for (int j = 0; j < 4; ++j) {
      int n = n0 + 64 * wc + 16 * j + l16;
      float bvv = bias[n];
#pragma unroll
      for (int r = 0; r < 4; ++r)
        Yf[(size_t)(mb + r) * N + n] = acc[i][j][r] + bvv;
    }
  }
}

// Partial gram: block bx -> bh = bx>>2, part = bx&3 (512-seq chunk).
// gram_p[bx][i][j] = sum_{s in chunk} K[bh][s][i] K[bh][s][j], fp32.
__global__ __launch_bounds__(256) void gram_mfma(
    const unsigned short* __restrict__ KTh, float* __restrict__ gram_p)
{
  __shared__ short KTs[64][136];
  const int t = threadIdx.x;
  const int lane = t & 63, w = t >> 6;
  const int quad = lane >> 4, l16 = lane & 15;
  const int bh = blockIdx.x >> 2, part = blockIdx.x & 3;
  const unsigned short* Kb = KTh + (size_t)bh * 131072 + part * 512;

  f32x4 gacc[4];
#pragma unroll
  for (int j = 0; j < 4; ++j) gacc[j] = fzero();

  const int rv = t >> 4, cv = (t & 15) * 8;
  for (int st = 0; st < 4; ++st) {
    float4 vv[4];
#pragma unroll
    for (int r = 0; r < 4; ++r)
      vv[r] = *(const float4*)&Kb[(size_t)(rv + 16 * r) * S_LEN + st * 128 + cv];
    __syncthreads();
#pragma unroll
    for (int r = 0; r < 4; ++r)
      *(float4*)&KTs[rv + 16 * r][cv] = vv[r];
    __syncthreads();
#pragma unroll
    for (int c = 0; c < 4; ++c) {
      bf16x8 ai = *(const bf16x8*)&KTs[16 * w + l16][32 * c + quad * 8];
#pragma unroll
      for (int jb = 0; jb < 4; ++jb) {
        bf16x8 bj = *(const bf16x8*)&KTs[16 * jb + l16][32 * c + quad * 8];
        gacc[jb] = __builtin_amdgcn_mfma_f32_16x16x32_bf16(ai, bj, gacc[jb], 0, 0, 0);
      }
    }
  }
#pragma unroll
  for (int jb = 0; jb < 4; ++jb)
#pragma unroll
    for (int r = 0; r < 4; ++r)
      gram_p[(size_t)blockIdx.x * 4096 +
             (size_t)(16 * w + quad * 4 + r) * 64 + 16 * jb + l16] = gacc[jb][r];
}

// In-place Gauss-Jordan inverse, 64x64 SPD (diag-dominant, no pivoting).
// One barrier per pivot: next pivot row/col exported during current update.
// Sums 4 gram partials on load. bf16 out.
__global__ __launch_bounds__(256) void inv_kernel(
    const float* __restrict__ gram_p, unsigned short* __restrict__ ginv)
{
  __shared__ float As[64][68];     // stride 68 floats: b128-aligned
  __shared__ float prow[2][64];    // raw (unscaled) pivot row, double-buffered
  __shared__ float fcol[2][64];    // pivot column, double-buffered
  const int bh = blockIdx.x;
  const int t = threadIdx.x;
  const int r = t >> 2;            // row 0..63
  const int c0 = (t & 3) * 16;     // 16-col segment
  const float* G = gram_p + (size_t)bh * 4 * 4096;

  float4 g[4];
#pragma unroll
  for (int jj = 0; jj < 4; ++jj) {
    int off = r * 64 + c0 + 4 * jj;
    float4 s0 = *(const float4*)&G[off];
    float4 s1 = *(const float4*)&G[4096 + off];
    float4 s2 = *(const float4*)&G[8192 + off];
    float4 s3 = *(const float4*)&G[12288 + off];
    g[jj].x = (s0.x + s1.x) + (s2.x + s3.x);
    g[jj].y = (s0.y + s1.y) + (s2.y + s3.y);
    g[jj].z = (s0.z + s1.z) + (s2.z + s3.z);
    g[jj].w = (s0.w + s1.w) + (s2.w + s3.w);
    *(float4*)&As[r][c0 + 4 * jj] = g[jj];
  }
  if (c0 == 0) fcol[0][r] = g[0].x;          // a[r][0]
  if (r == 0) {
#pragma unroll
    for (int jj = 0; jj < 4; ++jj) *(float4*)&prow[0][c0 + 4 * jj] = g[jj];
  }
  __syncthreads();

  for (int k = 0; k < 64; ++k) {
    const int kb = k & 1;
    const float f = fcol[kb][r];
    const float ip = 1.0f / fcol[kb][k];
    const float fi = f * ip;
    const bool pr = (r == k);
    float4 nv[4];
#pragma unroll
    for (int jj = 0; jj < 4; ++jj) {
      float4 a = *(const float4*)&As[r][c0 + 4 * jj];
      float4 p = *(const float4*)&prow[kb][c0 + 4 * jj];
      float4 o;
      if (pr) {
        o.x = p.x * ip; o.y = p.y * ip; o.z = p.z * ip; o.w = p.w * ip;
      } else {
        o.x = fmaf(-fi, p.x, a.x); o.y = fmaf(-fi, p.y, a.y);
        o.z = fmaf(-fi, p.z, a.z); o.w = fmaf(-fi, p.w, a.w);
      }
      const int cb = c0 + 4 * jj;
      const float kv = pr ? ip : -fi;
      if (cb == k) o.x = kv;
      if (cb + 1 == k) o.y = kv;
      if (cb + 2 == k) o.z = kv;
      if (cb + 3 == k) o.w = kv;
      *(float4*)&As[r][c0 + 4 * jj] = o;
      nv[jj] = o;
    }
    if (k < 63) {
      const int nk = k + 1, nb = nk & 1;
      if (nk >= c0 && nk < c0 + 16) fcol[nb][r] = As[r][nk];  // own fresh write
      if (r == nk) {
#pragma unroll
        for (int jj = 0; jj < 4; ++jj) *(float4*)&prow[nb][c0 + 4 * jj] = nv[jj];
      }
    }
    __syncthreads();
  }

  unsigned short* O = ginv + (size_t)bh * 4096;
#pragma unroll
  for (int jj = 0; jj < 4; ++jj) {
    float4 v = *(const float4*)&As[r][c0 + 4 * jj];
    uint2 pk;
    pk.x = (unsigned)f2bf(v.x) | ((unsigned)f2bf(v.y) << 16);
    pk.y = (unsigned)f2bf(v.z) | ((unsigned)f2bf(v.w) << 16);
    *(uint2*)&O[r * 64 + c0 + 4 * jj] = pk;
  }
}

// Fused flash: Qp = Q@Ginv; S^T = K@Qp^T; P=exp(S/32); O = P@V / rowsum.
__global__ __launch_bounds__(256) void flash_mfma(
    const unsigned short* __restrict__ Qh, const unsigned short* __restrict__ Kh,
    const unsigned short* __restrict__ VTh, const unsigned short* __restrict__ Ginv,
    unsigned short* __restrict__ AO)
{
  __shared__ short Ks[128][72];
  __shared__ short VTs[64][136];
  __shared__ short Ps[64][136];
  __shared__ short Qps[64][72];
  __shared__ float Lred[4][64];
  const int t = threadIdx.x;
  const int lane = t & 63, w = t >> 6;
  const int quad = lane >> 4, l16 = lane & 15;
  const int qt = blockIdx.x, bh = blockIdx.y;
  const unsigned short* Qb = Qh + (size_t)bh * 131072;
  const unsigned short* Kb = Kh + (size_t)bh * 131072;
  const unsigned short* Vb = VTh + (size_t)bh * 131072;
  short* G0 = &VTs[0][0];

  {
    int r0 = t >> 3, cq = (t & 7) * 8;
#pragma unroll
    for (int r = 0; r < 2; ++r) {
      int row = r0 + 32 * r;
      *(float4*)&Ks[row][cq] = *(const float4*)&Qb[(size_t)(qt * 64 + row) * 64 + cq];
      *(float4*)&G0[row * 72 + cq] = *(const float4*)&Ginv[(size_t)bh * 4096 + row * 64 + cq];
    }
  }
  __syncthreads();
  {
    f32x4 qacc[4];
#pragma unroll
    for (int nb = 0; nb < 4; ++nb) qacc[nb] = fzero();
#pragma unroll
    for (int c = 0; c < 2; ++c) {
      bf16x8 aq = *(const bf16x8*)&Ks[16 * w + l16][32 * c + quad * 8];
#pragma unroll
      for (int nb = 0; nb < 4; ++nb) {
        bf16x8 bg = *(const bf16x8*)&G0[(16 * nb + l16) * 72 + 32 * c + quad * 8];
        qacc[nb] = __builtin_amdgcn_mfma_f32_16x16x32_bf16(aq, bg, qacc[nb], 0, 0, 0);
      }
    }
    __syncthreads();
#pragma unroll
    for (int nb = 0; nb < 4; ++nb)
#pragma unroll
      for (int r = 0; r < 4; ++r)
        Qps[16 * w + quad * 4 + r][16 * nb + l16] = f2bf(qacc[nb][r]);
  }
  float lsum[4] = {0.0f, 0.0f, 0.0f, 0.0f};
  f32x4 oacc[4];
#pragma unroll
  for (int db = 0; db < 4; ++db) oacc[db] = fzero();
  __syncthreads();

  const float scale = 0.03125f;
  const int rk = t >> 3, ck = (t & 7) * 8;
  const int rv = t >> 4, cv = (t & 15) * 8;

  for (int kt = 0; kt < 16; ++kt) {
    float4 kv[4], vv[4];
#pragma unroll
    for (int r = 0; r < 4; ++r)
      kv[r] = *(const float4*)&Kb[(size_t)(kt * 128 + rk + 32 * r) * 64 + ck];
#pragma unroll
    for (int r = 0; r < 4; ++r)
      vv[r] = *(const float4*)&Vb[(size_t)(rv + 16 * r) * S_LEN + kt * 128 + cv];
#pragma unroll
    for (int r = 0; r < 4; ++r) *(float4*)&Ks[rk + 32 * r][ck] = kv[r];
#pragma unroll
    for (int r = 0; r < 4; ++r) *(float4*)&VTs[rv + 16 * r][cv] = vv[r];
    __syncthreads();

    f32x4 sacc[2][4];
#pragma unroll
    for (int kb = 0; kb < 2; ++kb)
#pragma unroll
      for (int qb = 0; qb < 4; ++qb) sacc[kb][qb] = fzero();
#pragma unroll
    for (int c = 0; c < 2; ++c) {
      bf16x8 ak0 = *(const bf16x8*)&Ks[32 * w + l16][32 * c + quad * 8];
      bf16x8 ak1 = *(const bf16x8*)&Ks[32 * w + 16 + l16][32 * c + quad * 8];
#pragma unroll
      for (int qb = 0; qb < 4; ++qb) {
        bf16x8 bq = *(const bf16x8*)&Qps[16 * qb + l16][32 * c + quad * 8];
        sacc[0][qb] = __builtin_amdgcn_mfma_f32_16x16x32_bf16(ak0, bq, sacc[0][qb], 0, 0, 0);
        sacc[1][qb] = __builtin_amdgcn_mfma_f32_16x16x32_bf16(ak1, bq, sacc[1][qb], 0, 0, 0);
      }
    }
#pragma unroll
    for (int kb = 0; kb < 2; ++kb)
#pragma unroll
      for (int qb = 0; qb < 4; ++qb) {
        float e0 = __expf(sacc[kb][qb][0] * scale);
        float e1 = __expf(sacc[kb][qb][1] * scale);
        float e2 = __expf(sacc[kb][qb][2] * scale);
        float e3 = __expf(sacc[kb][qb][3] * scale);
        lsum[qb] += (e0 + e1) + (e2 + e3);
        uint2 pk;
        pk.x = (unsigned)f2bf(e0) | ((unsigned)f2bf(e1) << 16);
        pk.y = (unsigned)f2bf(e2) | ((unsigned)f2bf(e3) << 16);
        *(uint2*)&Ps[16 * qb + l16][32 * w + 16 * kb + quad * 4] = pk;
      }
    __syncthreads();

#pragma unroll
    for (int c = 0; c < 4; ++c) {
      bf16x8 ap = *(const bf16x8*)&Ps[16 * w + l16][32 * c + quad * 8];
#pragma unroll
      for (int db = 0; db < 4; ++db) {
        bf16x8 bv = *(const bf16x8*)&VTs[16 * db + l16][32 * c + quad * 8];
        oacc[db] = __builtin_amdgcn_mfma_f32_16x16x32_bf16(ap, bv, oacc[db], 0, 0, 0);
      }
    }
    __syncthreads();
  }

#pragma unroll
  for (int qb = 0; qb < 4; ++qb) {
    lsum[qb] += __shfl_xor(lsum[qb], 16, 64);
    lsum[qb] += __shfl_xor(lsum[qb], 32, 64);
  }
  if (lane < 16)
#pragma unroll
    for (int qb = 0; qb < 4; ++qb) Lred[w][qb * 16 + l16] = lsum[qb];
  __syncthreads();
  if (t < 64)
    Lred[0][t] = 1.0f / (Lred[0][t] + Lred[1][t] + Lred[2][t] + Lred[3][t]);
  __syncthreads();

  const int b = bh >> 4, h = bh & 15;
#pragma unroll
  for (int r = 0; r < 4; ++r) {
    int q = 16 * w + quad * 4 + r;
    float li = Lred[0][q];
    int s = qt * 64 + q;
    size_t base = (size_t)b * S_LEN * EMB + (size_t)s * EMB + h * 64;
#pragma unroll
    for (int db = 0; db < 4; ++db)
      AO[base + 16 * db + l16] = f2bf(oacc[db][r] * li);
  }
}

extern "C" void kernel_launch(void* const* d_in, const int* in_sizes, int n_in,
                              void* d_out, int out_size, void* d_ws, size_t ws_size,
                              hipStream_t stream) {
  (void)in_sizes; (void)n_in; (void)out_size; (void)ws_size;
  const float* x   = (const float*)d_in[0];
  const float* Wq  = (const float*)d_in[1];
  const float* bq  = (const float*)d_in[2];
  const float* Wk  = (const float*)d_in[3];
  const float* bk  = (const float*)d_in[4];
  const float* Wv  = (const float*)d_in[5];
  const float* bv  = (const float*)d_in[6];
  const float* Wfc = (const float*)d_in[7];
  const float* bfc = (const float*)d_in[8];
  float* out = (float*)d_out;

  unsigned short* xb   = (unsigned short*)d_ws;            // [4096][1024]
  unsigned short* Wqb  = xb + (size_t)4194304;             // Wq,Wk,Wv,Wfc contiguous
  unsigned short* Wfcb = Wqb + 3 * 1048576;
  unsigned short* Qhd  = Wfcb + 1048576;                   // [32][2048][64]
  unsigned short* Khd  = Qhd + 4194304;
  unsigned short* KTd  = Khd + 4194304;                    // [32][64][2048]
  unsigned short* VTd  = KTd + 4194304;                    // [32][64][2048]
  unsigned short* AOd  = VTd + 4194304;                    // [2][2048][1024]
  float* gram_p        = (float*)(AOd + 4194304);          // [128][64][64] f32
  unsigned short* ginv = (unsigned short*)(gram_p + 524288); // [32][64][64] bf16

  cast_kernel<<<4096, 256, 0, stream>>>(x, Wq, Wk, Wv, Wfc, xb);
  gemm_qkv<<<dim3(8, 32, 3), 256, 0, stream>>>(xb, Wqb, bq, bk, bv,
                                               Qhd, Khd, KTd, VTd);
  gram_mfma<<<128, 256, 0, stream>>>(KTd, gram_p);
  inv_kernel<<<32, 256, 0, stream>>>(gram_p, ginv);
  flash_mfma<<<dim3(S_LEN / 64, 32), 256, 0, stream>>>(Qhd, Khd, VTd, ginv, AOd);
  gemm_fc<<<dim3(8, 32), 256, 0, stream>>>(AOd, Wfcb, bfc, out);
}